// Round 1
// baseline (5134.129 us; speedup 1.0000x reference)
//
#include <hip/hip_runtime.h>
#include <math.h>

#define Bn 64
#define Tn 256
#define Cn 384
#define Hn 6
#define HSn 64
#define FFn 1536
#define EPSn 1e-3f

// ---------------- LayerNorm (one block per row, 128 threads, 3 elems/thread) ----------------
__global__ __launch_bounds__(128) void ln_kernel(const float* __restrict__ x,
                                                 const float* __restrict__ g,
                                                 const float* __restrict__ be,
                                                 float* __restrict__ out) {
    int row = blockIdx.x;
    int tid = threadIdx.x;
    const float* xr = x + row * Cn;
    float v0 = xr[tid], v1 = xr[tid + 128], v2 = xr[tid + 256];
    float s = v0 + v1 + v2;
    __shared__ float red[4];
#pragma unroll
    for (int off = 32; off; off >>= 1) s += __shfl_xor(s, off);
    if ((tid & 63) == 0) red[tid >> 6] = s;
    __syncthreads();
    float mu = (red[0] + red[1]) * (1.0f / Cn);
    float d0 = v0 - mu, d1 = v1 - mu, d2 = v2 - mu;
    float sq = d0 * d0 + d1 * d1 + d2 * d2;
#pragma unroll
    for (int off = 32; off; off >>= 1) sq += __shfl_xor(sq, off);
    if ((tid & 63) == 0) red[2 + (tid >> 6)] = sq;
    __syncthreads();
    float var = (red[2] + red[3]) * (1.0f / Cn);
    float r = rsqrtf(var + EPSn);
    float* orow = out + row * Cn;
    orow[tid]       = d0 * r * g[tid]       + be[tid];
    orow[tid + 128] = d1 * r * g[tid + 128] + be[tid + 128];
    orow[tid + 256] = d2 * r * g[tid + 256] + be[tid + 256];
}

// ---------------- QKV projection: block = (t, head, b), 64 threads (one per HS dim) ----------------
__global__ __launch_bounds__(64) void qkv_kernel(const float* __restrict__ h,
                                                 const float* __restrict__ Wq,
                                                 const float* __restrict__ Wk,
                                                 const float* __restrict__ Wv,
                                                 float* __restrict__ q,
                                                 float* __restrict__ k,
                                                 float* __restrict__ v) {
    int t = blockIdx.x, head = blockIdx.y, b = blockIdx.z;
    int d = threadIdx.x;
    __shared__ float hrow[Cn];
    const float* hr = h + (b * Tn + t) * Cn;
#pragma unroll
    for (int i = d; i < Cn; i += 64) hrow[i] = hr[i];
    __syncthreads();
    const float* wq = Wq + head * Cn * HSn;
    const float* wk = Wk + head * Cn * HSn;
    const float* wv = Wv + head * Cn * HSn;
    float aq = 0.f, ak = 0.f, av = 0.f;
    for (int c = 0; c < Cn; c++) {
        float hv = hrow[c];
        aq += hv * wq[c * HSn + d];
        ak += hv * wk[c * HSn + d];
        av += hv * wv[c * HSn + d];
    }
    int idx = ((b * Hn + head) * Tn + t) * HSn + d;
    q[idx] = aq;
    k[idx] = ak;
    v[idx] = av;
}

// ---------------- Causal attention: block = (t, head, b), 64 threads = 1 wave ----------------
__global__ __launch_bounds__(64) void attn_kernel(const float* __restrict__ q,
                                                  const float* __restrict__ k,
                                                  const float* __restrict__ v,
                                                  float* __restrict__ o) {
    int t = blockIdx.x, head = blockIdx.y, b = blockIdx.z;
    int lane = threadIdx.x;
    __shared__ float qrow[HSn];
    __shared__ float p[Tn];
    const float* qp = q + ((b * Hn + head) * Tn + t) * HSn;
    qrow[lane] = qp[lane];
    __syncthreads();
    const float* kb = k + (b * Hn + head) * Tn * HSn;
    float m = -INFINITY;
    float sc[4];
#pragma unroll
    for (int j = 0; j < 4; j++) {
        int s = lane + j * 64;
        float a = -INFINITY;
        if (s <= t) {
            const float* kr = kb + s * HSn;
            float acc = 0.f;
            for (int c = 0; c < HSn; c++) acc += qrow[c] * kr[c];
            a = acc * 0.125f;  // HS^-0.5
        }
        sc[j] = a;
        m = fmaxf(m, a);
    }
#pragma unroll
    for (int off = 32; off; off >>= 1) m = fmaxf(m, __shfl_xor(m, off));
    float sum = 0.f;
#pragma unroll
    for (int j = 0; j < 4; j++) {
        int s = lane + j * 64;
        float e = (s <= t) ? __expf(sc[j] - m) : 0.0f;
        p[s] = e;
        sum += e;
    }
#pragma unroll
    for (int off = 32; off; off >>= 1) sum += __shfl_xor(sum, off);
    float inv = 1.0f / sum;
    __syncthreads();
    const float* vb = v + (b * Hn + head) * Tn * HSn;
    float acc = 0.f;
    for (int s = 0; s <= t; s++) acc += p[s] * vb[s * HSn + lane];
    acc *= inv;
    // 'bthd' concat layout -> [B,T,C]
    o[((b * Tn + t) * Hn + head) * HSn + lane] = acc;
}

// ---------------- Output projection + residual: x2 = x + o@Wp + bp ----------------
__global__ __launch_bounds__(128) void proj_kernel(const float* __restrict__ x,
                                                   const float* __restrict__ o,
                                                   const float* __restrict__ Wp,
                                                   const float* __restrict__ bp,
                                                   float* __restrict__ x2) {
    int row = blockIdx.x;
    int tid = threadIdx.x;
    __shared__ float orow[Cn];
    const float* orp = o + row * Cn;
    orow[tid] = orp[tid];
    orow[tid + 128] = orp[tid + 128];
    orow[tid + 256] = orp[tid + 256];
    __syncthreads();
    float a0 = 0.f, a1 = 0.f, a2 = 0.f;
    for (int kk = 0; kk < Cn; kk++) {
        float ov = orow[kk];
        const float* wr = Wp + kk * Cn;
        a0 += ov * wr[tid];
        a1 += ov * wr[tid + 128];
        a2 += ov * wr[tid + 256];
    }
    const float* xr = x + row * Cn;
    float* xo = x2 + row * Cn;
    xo[tid]       = xr[tid]       + a0 + bp[tid];
    xo[tid + 128] = xr[tid + 128] + a1 + bp[tid + 128];
    xo[tid + 256] = xr[tid + 256] + a2 + bp[tid + 256];
}

// ---------------- Fused: LN2 + FF1 + ReLU + FF2 + residual (in-place on d_out) ----------------
__global__ __launch_bounds__(256) void ff_kernel(const float* __restrict__ x2,
                                                 const float* __restrict__ g,
                                                 const float* __restrict__ be,
                                                 const float* __restrict__ W1,
                                                 const float* __restrict__ b1,
                                                 const float* __restrict__ W2,
                                                 const float* __restrict__ b2,
                                                 float* __restrict__ out) {
    int row = blockIdx.x;
    int tid = threadIdx.x;
    __shared__ float h2[Cn];
    __shared__ float y1[FFn];
    __shared__ float red[8];
    const float* xr = x2 + row * Cn;
    float v0 = xr[tid];
    float v1 = (tid < 128) ? xr[tid + 256] : 0.0f;
    float s = v0 + v1;
#pragma unroll
    for (int off = 32; off; off >>= 1) s += __shfl_xor(s, off);
    if ((tid & 63) == 0) red[tid >> 6] = s;
    __syncthreads();
    float mu = (red[0] + red[1] + red[2] + red[3]) * (1.0f / Cn);
    float d0 = v0 - mu;
    float d1 = v1 - mu;
    float sq = d0 * d0 + ((tid < 128) ? d1 * d1 : 0.0f);
#pragma unroll
    for (int off = 32; off; off >>= 1) sq += __shfl_xor(sq, off);
    if ((tid & 63) == 0) red[4 + (tid >> 6)] = sq;
    __syncthreads();
    float var = (red[4] + red[5] + red[6] + red[7]) * (1.0f / Cn);
    float r = rsqrtf(var + EPSn);
    h2[tid] = d0 * r * g[tid] + be[tid];
    if (tid < 128) h2[tid + 256] = d1 * r * g[tid + 256] + be[tid + 256];
    __syncthreads();
    // FF1 + ReLU: 1536 outputs, 6 per thread
#pragma unroll
    for (int j0 = 0; j0 < 6; j0++) {
        int j = tid + j0 * 256;
        float a = 0.f;
        for (int c = 0; c < Cn; c++) a += h2[c] * W1[c * FFn + j];
        a += b1[j];
        y1[j] = fmaxf(a, 0.0f);
    }
    __syncthreads();
    // FF2 + residual: 384 outputs
    float accA = 0.f, accB = 0.f;
    for (int kk = 0; kk < FFn; kk++) {
        float yv = y1[kk];
        const float* wr = W2 + kk * Cn;
        accA += yv * wr[tid];
        if (tid < 128) accB += yv * wr[tid + 256];
    }
    float* orow = out + row * Cn;
    orow[tid] = xr[tid] + accA + b2[tid];
    if (tid < 128) orow[tid + 256] = xr[tid + 256] + accB + b2[tid + 256];
}

extern "C" void kernel_launch(void* const* d_in, const int* in_sizes, int n_in,
                              void* d_out, int out_size, void* d_ws, size_t ws_size,
                              hipStream_t stream) {
    const float* x  = (const float*)d_in[0];
    const float* Wq = (const float*)d_in[1];
    const float* Wk = (const float*)d_in[2];
    const float* Wv = (const float*)d_in[3];
    const float* Wp = (const float*)d_in[4];
    const float* bp = (const float*)d_in[5];
    const float* W1 = (const float*)d_in[6];
    const float* b1 = (const float*)d_in[7];
    const float* W2 = (const float*)d_in[8];
    const float* b2 = (const float*)d_in[9];
    const float* g1 = (const float*)d_in[10];
    const float* be1 = (const float*)d_in[11];
    const float* g2 = (const float*)d_in[12];
    const float* be2 = (const float*)d_in[13];

    const size_t NBTC = (size_t)Bn * Tn * Cn;  // 6,291,456
    float* h = (float*)d_ws;            // [B,T,C]   (reused as attention output o)
    float* q = h + NBTC;                // [B,H,T,HS]
    float* k = q + NBTC;
    float* v = k + NBTC;
    float* x2 = (float*)d_out;          // residual-1 result staged in d_out

    // 1) h = LN1(x)
    ln_kernel<<<Bn * Tn, 128, 0, stream>>>(x, g1, be1, h);
    // 2) q,k,v
    qkv_kernel<<<dim3(Tn, Hn, Bn), 64, 0, stream>>>(h, Wq, Wk, Wv, q, k, v);
    // 3) attention -> o (reuses h buffer)
    attn_kernel<<<dim3(Tn, Hn, Bn), 64, 0, stream>>>(q, k, v, h);
    // 4) x2 = x + o@Wp + bp  (into d_out)
    proj_kernel<<<Bn * Tn, 128, 0, stream>>>(x, h, Wp, bp, x2);
    // 5) out = x2 + FF(LN2(x2))  (in place on d_out)
    ff_kernel<<<Bn * Tn, 256, 0, stream>>>(x2, g2, be2, W1, b1, W2, b2, (float*)d_out);
}

// Round 2
// 673.870 us; speedup vs baseline: 7.6189x; 7.6189x over previous
//
#include <hip/hip_runtime.h>
#include <hip/hip_bf16.h>
#include <math.h>

#define Bn 64
#define Tn 256
#define Cn 384
#define Hn 6
#define HSn 64
#define FFn 1536
#define EPSn 1e-3f
#define SECn 6291456  // B*H*T*HS = one q/k/v section, elements

typedef __attribute__((ext_vector_type(4))) float f32x4;
typedef __attribute__((ext_vector_type(8))) short short8;

// ---------------- LayerNorm -> bf16 (one block per row, 128 threads) ----------------
__global__ __launch_bounds__(128) void ln_bf16_kernel(const float* __restrict__ x,
                                                      const float* __restrict__ g,
                                                      const float* __restrict__ be,
                                                      __hip_bfloat16* __restrict__ out) {
    int row = blockIdx.x;
    int tid = threadIdx.x;
    const float* xr = x + (size_t)row * Cn;
    float v0 = xr[tid], v1 = xr[tid + 128], v2 = xr[tid + 256];
    float s = v0 + v1 + v2;
    __shared__ float red[4];
#pragma unroll
    for (int off = 32; off; off >>= 1) s += __shfl_xor(s, off);
    if ((tid & 63) == 0) red[tid >> 6] = s;
    __syncthreads();
    float mu = (red[0] + red[1]) * (1.0f / Cn);
    float d0 = v0 - mu, d1 = v1 - mu, d2 = v2 - mu;
    float sq = d0 * d0 + d1 * d1 + d2 * d2;
#pragma unroll
    for (int off = 32; off; off >>= 1) sq += __shfl_xor(sq, off);
    if ((tid & 63) == 0) red[2 + (tid >> 6)] = sq;
    __syncthreads();
    float var = (red[2] + red[3]) * (1.0f / Cn);
    float r = rsqrtf(var + EPSn);
    __hip_bfloat16* orow = out + (size_t)row * Cn;
    orow[tid]       = __float2bfloat16(d0 * r * g[tid]       + be[tid]);
    orow[tid + 128] = __float2bfloat16(d1 * r * g[tid + 128] + be[tid + 128]);
    orow[tid + 256] = __float2bfloat16(d2 * r * g[tid + 256] + be[tid + 256]);
}

// ---------------- Pack a [K,N] row-major fp32 weight into MFMA B-fragment order ----------------
// Layout: tile = (kb/32)*(N/16) + (nt/16); elem = tile*512 + lane*8 + j
//         value = W[kb + (lane>>4)*8 + j][nt + (lane&15)]
__global__ __launch_bounds__(256) void pack_b_kernel(const float* __restrict__ W,
                                                     __hip_bfloat16* __restrict__ out,
                                                     int K, int N) {
    int id = blockIdx.x * 256 + threadIdx.x;
    if (id >= K * N) return;
    int tile = id >> 9, lane = (id >> 3) & 63, j = id & 7;
    int ntiles = N >> 4;
    int k = (tile / ntiles) * 32 + ((lane >> 4) << 3) + j;
    int n = (tile % ntiles) * 16 + (lane & 15);
    out[id] = __float2bfloat16(W[(size_t)k * N + n]);
}

// ---------------- Pack fused [Wq|Wk|Wv] into one B [K=384, N=1152] ----------------
// col n: section = n/384 (q/k/v), head = (n%384)/64, d = n%64
__global__ __launch_bounds__(256) void pack_qkv_kernel(const float* __restrict__ Wq,
                                                       const float* __restrict__ Wk,
                                                       const float* __restrict__ Wv,
                                                       __hip_bfloat16* __restrict__ out) {
    int id = blockIdx.x * 256 + threadIdx.x;
    if (id >= Cn * 1152) return;
    int tile = id >> 9, lane = (id >> 3) & 63, j = id & 7;
    int k = (tile / 72) * 32 + ((lane >> 4) << 3) + j;
    int n = (tile % 72) * 16 + (lane & 15);
    int sec = n / Cn, rem = n % Cn;
    int hh = rem >> 6, d = rem & 63;
    const float* W = (sec == 0) ? Wq : ((sec == 1) ? Wk : Wv);
    out[id] = __float2bfloat16(W[((size_t)hh * Cn + k) * HSn + d]);
}

// ---------------- MFMA GEMM: C[M,NN] = A[M,KK](bf16,row-major) @ Bpacked ----------------
// EPI 0: scatter bf16 into q/k/v sections [B,H,T,HS]   (outB = base of q)
// EPI 1: outF = resid + acc + bias (fp32)
// EPI 2: outB = bf16(relu(acc + bias))  row-major [M,NN]
template <int KK, int NN, int EPI>
__global__ __launch_bounds__(256) void gemm_mfma(const __hip_bfloat16* __restrict__ A,
                                                 const __hip_bfloat16* __restrict__ Bp,
                                                 const float* __restrict__ bias,
                                                 const float* __restrict__ resid,
                                                 float* __restrict__ outF,
                                                 __hip_bfloat16* __restrict__ outB) {
    int lane = threadIdx.x & 63, wave = threadIdx.x >> 6;
    int lrow = lane & 15, lquad = lane >> 4;
    int m0 = blockIdx.y * 64 + wave * 16;
    int n0 = blockIdx.x * 64;

    f32x4 acc[4] = {};
    const short* As = (const short*)A;
    const short* Bs = (const short*)Bp;
    const short* arow = As + (size_t)(m0 + lrow) * KK + lquad * 8;

    for (int kb = 0; kb < KK; kb += 32) {
        short8 af = *(const short8*)(arow + kb);
        int tb = (kb >> 5) * (NN >> 4) + (n0 >> 4);
#pragma unroll
        for (int nt = 0; nt < 4; nt++) {
            short8 bf = *(const short8*)(Bs + (size_t)(tb + nt) * 512 + lane * 8);
            acc[nt] = __builtin_amdgcn_mfma_f32_16x16x32_bf16(af, bf, acc[nt], 0, 0, 0);
        }
    }

#pragma unroll
    for (int nt = 0; nt < 4; nt++) {
        int n = n0 + nt * 16 + lrow;
#pragma unroll
        for (int r = 0; r < 4; r++) {
            int m = m0 + lquad * 4 + r;
            float vv = acc[nt][r];
            if (EPI == 0) {
                int b = m >> 8, t = m & 255;
                int sec = n / Cn, rem = n % Cn;
                int hh = rem >> 6, d = rem & 63;
                outB[(size_t)sec * SECn + ((((size_t)b * Hn + hh) << 8) + t) * HSn + d] =
                    __float2bfloat16(vv);
            } else if (EPI == 1) {
                size_t idx = (size_t)m * NN + n;
                outF[idx] = resid[idx] + vv + bias[n];
            } else {
                float y = vv + bias[n];
                outB[(size_t)m * NN + n] = __float2bfloat16(fmaxf(y, 0.0f));
            }
        }
    }
}

// ---------------- Causal attention (scalar, bf16 in/out): block = (t, head, b), 1 wave ----------------
__global__ __launch_bounds__(64) void attn_kernel(const __hip_bfloat16* __restrict__ q,
                                                  const __hip_bfloat16* __restrict__ k,
                                                  const __hip_bfloat16* __restrict__ v,
                                                  __hip_bfloat16* __restrict__ o) {
    int t = blockIdx.x, head = blockIdx.y, b = blockIdx.z;
    int lane = threadIdx.x;
    __shared__ float qrow[HSn];
    __shared__ float p[Tn];
    const __hip_bfloat16* qp = q + (((size_t)(b * Hn + head) * Tn) + t) * HSn;
    qrow[lane] = __bfloat162float(qp[lane]);
    __syncthreads();
    const __hip_bfloat16* kb = k + (size_t)(b * Hn + head) * Tn * HSn;
    float m = -INFINITY;
    float sc[4];
#pragma unroll
    for (int j = 0; j < 4; j++) {
        int s = lane + j * 64;
        float a = -INFINITY;
        if (s <= t) {
            const __hip_bfloat16* kr = kb + (size_t)s * HSn;
            float acc = 0.f;
            for (int c = 0; c < HSn; c++) acc += qrow[c] * __bfloat162float(kr[c]);
            a = acc * 0.125f;
        }
        sc[j] = a;
        m = fmaxf(m, a);
    }
#pragma unroll
    for (int off = 32; off; off >>= 1) m = fmaxf(m, __shfl_xor(m, off));
    float sum = 0.f;
#pragma unroll
    for (int j = 0; j < 4; j++) {
        int s = lane + j * 64;
        float e = (s <= t) ? __expf(sc[j] - m) : 0.0f;
        p[s] = e;
        sum += e;
    }
#pragma unroll
    for (int off = 32; off; off >>= 1) sum += __shfl_xor(sum, off);
    float inv = 1.0f / sum;
    __syncthreads();
    const __hip_bfloat16* vb = v + (size_t)(b * Hn + head) * Tn * HSn;
    float acc = 0.f;
    for (int s = 0; s <= t; s++) acc += p[s] * __bfloat162float(vb[(size_t)s * HSn + lane]);
    acc *= inv;
    o[(((size_t)(b * Tn + t) * Hn) + head) * HSn + lane] = __float2bfloat16(acc);
}

extern "C" void kernel_launch(void* const* d_in, const int* in_sizes, int n_in,
                              void* d_out, int out_size, void* d_ws, size_t ws_size,
                              hipStream_t stream) {
    const float* x  = (const float*)d_in[0];
    const float* Wq = (const float*)d_in[1];
    const float* Wk = (const float*)d_in[2];
    const float* Wv = (const float*)d_in[3];
    const float* Wp = (const float*)d_in[4];
    const float* bp = (const float*)d_in[5];
    const float* W1 = (const float*)d_in[6];
    const float* b1 = (const float*)d_in[7];
    const float* W2 = (const float*)d_in[8];
    const float* b2 = (const float*)d_in[9];
    const float* g1 = (const float*)d_in[10];
    const float* be1 = (const float*)d_in[11];
    const float* g2 = (const float*)d_in[12];
    const float* be2 = (const float*)d_in[13];

    const size_t M = (size_t)Bn * Tn;  // 16384
    __hip_bfloat16* ws  = (__hip_bfloat16*)d_ws;
    __hip_bfloat16* h   = ws;               // M*384 bf16 (LN1 out; reused as h2 for LN2)
    __hip_bfloat16* big = h + M * Cn;       // M*1536 bf16 region: qkv (3*SECn) then y1
    __hip_bfloat16* o   = big + M * FFn;    // M*384 bf16 attention output [b,t,h,d]
    __hip_bfloat16* pQKV = o + M * Cn;      // 384*1152
    __hip_bfloat16* pWp  = pQKV + Cn * 1152;  // 384*384
    __hip_bfloat16* pW1  = pWp + Cn * Cn;     // 384*1536
    __hip_bfloat16* pW2  = pW1 + Cn * FFn;    // 1536*384

    float* x2 = (float*)d_out;

    // weight packing (per-call; ws is re-poisoned every launch)
    pack_qkv_kernel<<<(Cn * 1152 + 255) / 256, 256, 0, stream>>>(Wq, Wk, Wv, pQKV);
    pack_b_kernel<<<(Cn * Cn + 255) / 256, 256, 0, stream>>>(Wp, pWp, Cn, Cn);
    pack_b_kernel<<<(Cn * FFn + 255) / 256, 256, 0, stream>>>(W1, pW1, Cn, FFn);
    pack_b_kernel<<<(FFn * Cn + 255) / 256, 256, 0, stream>>>(W2, pW2, FFn, Cn);

    // 1) h = LN1(x)  (bf16)
    ln_bf16_kernel<<<M, 128, 0, stream>>>(x, g1, be1, h);
    // 2) qkv = h @ [Wq|Wk|Wv]  -> scattered bf16 [B,H,T,HS] sections
    gemm_mfma<Cn, 1152, 0><<<dim3(18, 256), 256, 0, stream>>>(h, pQKV, nullptr, nullptr, nullptr, big);
    // 3) attention -> o bf16 [b,t,h,d]
    attn_kernel<<<dim3(Tn, Hn, Bn), 64, 0, stream>>>(big, big + SECn, big + 2 * SECn, o);
    // 4) x2 = x + o@Wp + bp  (fp32, into d_out)
    gemm_mfma<Cn, Cn, 1><<<dim3(6, 256), 256, 0, stream>>>(o, pWp, bp, x, x2, nullptr);
    // 5) h2 = LN2(x2)  (bf16, reuse h buffer)
    ln_bf16_kernel<<<M, 128, 0, stream>>>(x2, g2, be2, h);
    // 6) y1 = relu(h2 @ W1 + b1)  (bf16, reuses qkv region)
    gemm_mfma<Cn, FFn, 2><<<dim3(24, 256), 256, 0, stream>>>(h, pW1, b1, nullptr, nullptr, big);
    // 7) out = x2 + y1 @ W2 + b2  (fp32, in place on d_out)
    gemm_mfma<FFn, Cn, 1><<<dim3(6, 256), 256, 0, stream>>>(big, pW2, b2, x2, x2, nullptr);
}

// Round 3
// 405.735 us; speedup vs baseline: 12.6539x; 1.6609x over previous
//
#include <hip/hip_runtime.h>
#include <hip/hip_bf16.h>
#include <math.h>

#define Bn 64
#define Tn 256
#define Cn 384
#define Hn 6
#define HSn 64
#define FFn 1536
#define EPSn 1e-3f
#define SECn 6291456  // B*H*T*HS = one q/k/v section, elements

typedef __attribute__((ext_vector_type(4))) float f32x4;
typedef __attribute__((ext_vector_type(8))) short short8;

// ---------------- LayerNorm -> bf16 (one block per row, 128 threads) ----------------
__global__ __launch_bounds__(128) void ln_bf16_kernel(const float* __restrict__ x,
                                                      const float* __restrict__ g,
                                                      const float* __restrict__ be,
                                                      __hip_bfloat16* __restrict__ out) {
    int row = blockIdx.x;
    int tid = threadIdx.x;
    const float* xr = x + (size_t)row * Cn;
    float v0 = xr[tid], v1 = xr[tid + 128], v2 = xr[tid + 256];
    float s = v0 + v1 + v2;
    __shared__ float red[4];
#pragma unroll
    for (int off = 32; off; off >>= 1) s += __shfl_xor(s, off);
    if ((tid & 63) == 0) red[tid >> 6] = s;
    __syncthreads();
    float mu = (red[0] + red[1]) * (1.0f / Cn);
    float d0 = v0 - mu, d1 = v1 - mu, d2 = v2 - mu;
    float sq = d0 * d0 + d1 * d1 + d2 * d2;
#pragma unroll
    for (int off = 32; off; off >>= 1) sq += __shfl_xor(sq, off);
    if ((tid & 63) == 0) red[2 + (tid >> 6)] = sq;
    __syncthreads();
    float var = (red[2] + red[3]) * (1.0f / Cn);
    float r = rsqrtf(var + EPSn);
    __hip_bfloat16* orow = out + (size_t)row * Cn;
    orow[tid]       = __float2bfloat16(d0 * r * g[tid]       + be[tid]);
    orow[tid + 128] = __float2bfloat16(d1 * r * g[tid + 128] + be[tid + 128]);
    orow[tid + 256] = __float2bfloat16(d2 * r * g[tid + 256] + be[tid + 256]);
}

// ---------------- Pack a [K,N] row-major fp32 weight into MFMA B-fragment order ----------------
__global__ __launch_bounds__(256) void pack_b_kernel(const float* __restrict__ W,
                                                     __hip_bfloat16* __restrict__ out,
                                                     int K, int N) {
    int id = blockIdx.x * 256 + threadIdx.x;
    if (id >= K * N) return;
    int tile = id >> 9, lane = (id >> 3) & 63, j = id & 7;
    int ntiles = N >> 4;
    int k = (tile / ntiles) * 32 + ((lane >> 4) << 3) + j;
    int n = (tile % ntiles) * 16 + (lane & 15);
    out[id] = __float2bfloat16(W[(size_t)k * N + n]);
}

// ---------------- Pack fused [Wq|Wk|Wv] into one B [K=384, N=1152] ----------------
__global__ __launch_bounds__(256) void pack_qkv_kernel(const float* __restrict__ Wq,
                                                       const float* __restrict__ Wk,
                                                       const float* __restrict__ Wv,
                                                       __hip_bfloat16* __restrict__ out) {
    int id = blockIdx.x * 256 + threadIdx.x;
    if (id >= Cn * 1152) return;
    int tile = id >> 9, lane = (id >> 3) & 63, j = id & 7;
    int k = (tile / 72) * 32 + ((lane >> 4) << 3) + j;
    int n = (tile % 72) * 16 + (lane & 15);
    int sec = n / Cn, rem = n % Cn;
    int hh = rem >> 6, d = rem & 63;
    const float* W = (sec == 0) ? Wq : ((sec == 1) ? Wk : Wv);
    out[id] = __float2bfloat16(W[((size_t)hh * Cn + k) * HSn + d]);
}

// ---------------- MFMA GEMM: C[M,NN] = A[M,KK](bf16,row-major) @ Bpacked ----------------
template <int KK, int NN, int EPI>
__global__ __launch_bounds__(256) void gemm_mfma(const __hip_bfloat16* __restrict__ A,
                                                 const __hip_bfloat16* __restrict__ Bp,
                                                 const float* __restrict__ bias,
                                                 const float* __restrict__ resid,
                                                 float* __restrict__ outF,
                                                 __hip_bfloat16* __restrict__ outB) {
    int lane = threadIdx.x & 63, wave = threadIdx.x >> 6;
    int lrow = lane & 15, lquad = lane >> 4;
    int m0 = blockIdx.y * 64 + wave * 16;
    int n0 = blockIdx.x * 64;

    f32x4 acc[4] = {};
    const short* As = (const short*)A;
    const short* Bs = (const short*)Bp;
    const short* arow = As + (size_t)(m0 + lrow) * KK + lquad * 8;

    for (int kb = 0; kb < KK; kb += 32) {
        short8 af = *(const short8*)(arow + kb);
        int tb = (kb >> 5) * (NN >> 4) + (n0 >> 4);
#pragma unroll
        for (int nt = 0; nt < 4; nt++) {
            short8 bf = *(const short8*)(Bs + (size_t)(tb + nt) * 512 + lane * 8);
            acc[nt] = __builtin_amdgcn_mfma_f32_16x16x32_bf16(af, bf, acc[nt], 0, 0, 0);
        }
    }

#pragma unroll
    for (int nt = 0; nt < 4; nt++) {
        int n = n0 + nt * 16 + lrow;
#pragma unroll
        for (int r = 0; r < 4; r++) {
            int m = m0 + lquad * 4 + r;
            float vv = acc[nt][r];
            if (EPI == 0) {
                int b = m >> 8, t = m & 255;
                int sec = n / Cn, rem = n % Cn;
                int hh = rem >> 6, d = rem & 63;
                outB[(size_t)sec * SECn + ((((size_t)b * Hn + hh) << 8) + t) * HSn + d] =
                    __float2bfloat16(vv);
            } else if (EPI == 1) {
                size_t idx = (size_t)m * NN + n;
                outF[idx] = resid[idx] + vv + bias[n];
            } else {
                float y = vv + bias[n];
                outB[(size_t)m * NN + n] = __float2bfloat16(fmaxf(y, 0.0f));
            }
        }
    }
}

// ---------------- Flash-style MFMA attention ----------------
// grid (4, B*H); block 256 = 4 waves; wave w owns Q rows [qb*64+w*16, +16)
// V staged in LDS as packed B-fragments; P round-trips LDS in packed A-fragments.
__global__ __launch_bounds__(256) void attn_mfma_kernel(const __hip_bfloat16* __restrict__ q,
                                                        const __hip_bfloat16* __restrict__ k,
                                                        const __hip_bfloat16* __restrict__ v,
                                                        __hip_bfloat16* __restrict__ o) {
    __shared__ short Vp[16384];  // 32 KB: V in B-fragment packed layout
    __shared__ short Pp[16384];  // 32 KB: per-wave P in A-fragment packed layout
    int qb = blockIdx.x;
    int bh = blockIdx.y;
    int b = bh / Hn, hh = bh - b * Hn;
    int tid = threadIdx.x;
    int lane = tid & 63, wave = tid >> 6;
    int c16 = lane & 15, quad = lane >> 4;

    const short* qs = (const short*)q + (size_t)bh * Tn * HSn;
    const short* ks = (const short*)k + (size_t)bh * Tn * HSn;
    const short* vs = (const short*)v + (size_t)bh * Tn * HSn;

    // ---- stage V into packed B-fragment layout ----
    // elem(tile, lane_v, j): tile=(s>>5)*4+(d>>4), lane_v=((s>>3)&3)*16+(d&15), j=s&7
#pragma unroll
    for (int i = 0; i < 8; i++) {
        int cid = i * 256 + tid;
        int s = cid >> 3, d0 = (cid & 7) * 8;
        short8 vv = *(const short8*)(vs + s * HSn + d0);
        int lv_base = ((s >> 3) & 3) * 16;
        int j = s & 7;
        int tile_s = (s >> 5) * 4;
#pragma unroll
        for (int jj = 0; jj < 8; jj++) {
            int d = d0 + jj;
            Vp[(tile_s + (d >> 4)) * 512 + (lv_base + (d & 15)) * 8 + j] = vv[jj];
        }
    }
    __syncthreads();

    int qrow0 = qb * 64 + wave * 16;
    int st_max = qb * 4 + wave;            // highest score tile with any valid col
    int kb_count = (st_max + 2) >> 1;      // 32-wide k-blocks for PV
    int covered = kb_count * 2;            // P tiles PV will read (zero-fill beyond st_max)

    // Q A-fragments from global
    const short* qrow = qs + (qrow0 + c16) * HSn + quad * 8;
    short8 aq0 = *(const short8*)(qrow);
    short8 aq1 = *(const short8*)(qrow + 32);

    // ---- S = Q K^T (scaled later) ----
    f32x4 accS[16];
#pragma unroll
    for (int st = 0; st < 16; st++) accS[st] = (f32x4){0.f, 0.f, 0.f, 0.f};
#pragma unroll
    for (int st = 0; st < 16; st++) {
        if (st <= st_max) {
            const short* kr = ks + (st * 16 + c16) * HSn + quad * 8;
            short8 bk0 = *(const short8*)(kr);
            short8 bk1 = *(const short8*)(kr + 32);
            accS[st] = __builtin_amdgcn_mfma_f32_16x16x32_bf16(aq0, bk0, accS[st], 0, 0, 0);
            accS[st] = __builtin_amdgcn_mfma_f32_16x16x32_bf16(aq1, bk1, accS[st], 0, 0, 0);
        }
    }

    // ---- softmax (per quad-row), write unnormalized P to LDS in A-frag layout ----
    short* Pw = Pp + wave * 4096;
    float inv[4];
#pragma unroll
    for (int r = 0; r < 4; r++) {
        int row = qrow0 + quad * 4 + r;
        float mx = -INFINITY;
#pragma unroll
        for (int st = 0; st < 16; st++) {
            if (st <= st_max) {
                int col = st * 16 + c16;
                float a = (col <= row) ? accS[st][r] * 0.125f : -INFINITY;
                accS[st][r] = a;
                mx = fmaxf(mx, a);
            }
        }
#pragma unroll
        for (int off = 8; off; off >>= 1) mx = fmaxf(mx, __shfl_xor(mx, off));
        float sum = 0.f;
#pragma unroll
        for (int st = 0; st < 16; st++) {
            if (st < covered) {
                float e = 0.0f;
                if (st <= st_max) {
                    e = __expf(accS[st][r] - mx);
                    sum += e;
                }
                int c = st * 16 + c16;
                __hip_bfloat16 pb = __float2bfloat16(e);
                Pw[(c >> 5) * 512 + (((c >> 3) & 3) * 16 + quad * 4 + r) * 8 + (c & 7)] =
                    *(short*)&pb;
            }
        }
#pragma unroll
        for (int off = 8; off; off >>= 1) sum += __shfl_xor(sum, off);
        inv[r] = 1.0f / sum;
    }

    // ---- O = P V ----
    f32x4 accO[4];
#pragma unroll
    for (int nt = 0; nt < 4; nt++) accO[nt] = (f32x4){0.f, 0.f, 0.f, 0.f};
#pragma unroll
    for (int kbi = 0; kbi < 8; kbi++) {
        if (kbi < kb_count) {
            short8 ap = *(const short8*)(Pw + kbi * 512 + lane * 8);
#pragma unroll
            for (int nt = 0; nt < 4; nt++) {
                short8 bv = *(const short8*)(Vp + (kbi * 4 + nt) * 512 + lane * 8);
                accO[nt] = __builtin_amdgcn_mfma_f32_16x16x32_bf16(ap, bv, accO[nt], 0, 0, 0);
            }
        }
    }

    // ---- epilogue: normalize, write o[b,t,h,d] ----
#pragma unroll
    for (int nt = 0; nt < 4; nt++) {
#pragma unroll
        for (int r = 0; r < 4; r++) {
            int t = qrow0 + quad * 4 + r;
            int d = nt * 16 + c16;
            o[(((size_t)b * Tn + t) * Hn + hh) * HSn + d] = __float2bfloat16(accO[nt][r] * inv[r]);
        }
    }
}

extern "C" void kernel_launch(void* const* d_in, const int* in_sizes, int n_in,
                              void* d_out, int out_size, void* d_ws, size_t ws_size,
                              hipStream_t stream) {
    const float* x  = (const float*)d_in[0];
    const float* Wq = (const float*)d_in[1];
    const float* Wk = (const float*)d_in[2];
    const float* Wv = (const float*)d_in[3];
    const float* Wp = (const float*)d_in[4];
    const float* bp = (const float*)d_in[5];
    const float* W1 = (const float*)d_in[6];
    const float* b1 = (const float*)d_in[7];
    const float* W2 = (const float*)d_in[8];
    const float* b2 = (const float*)d_in[9];
    const float* g1 = (const float*)d_in[10];
    const float* be1 = (const float*)d_in[11];
    const float* g2 = (const float*)d_in[12];
    const float* be2 = (const float*)d_in[13];

    const size_t M = (size_t)Bn * Tn;  // 16384
    __hip_bfloat16* ws  = (__hip_bfloat16*)d_ws;
    __hip_bfloat16* h   = ws;               // M*384 bf16 (LN1 out; reused as h2)
    __hip_bfloat16* big = h + M * Cn;       // M*1536 bf16: qkv (3*SECn) then y1
    __hip_bfloat16* o   = big + M * FFn;    // M*384 bf16 attention output [b,t,h,d]
    __hip_bfloat16* pQKV = o + M * Cn;      // 384*1152
    __hip_bfloat16* pWp  = pQKV + Cn * 1152;
    __hip_bfloat16* pW1  = pWp + Cn * Cn;
    __hip_bfloat16* pW2  = pW1 + Cn * FFn;

    float* x2 = (float*)d_out;

    pack_qkv_kernel<<<(Cn * 1152 + 255) / 256, 256, 0, stream>>>(Wq, Wk, Wv, pQKV);
    pack_b_kernel<<<(Cn * Cn + 255) / 256, 256, 0, stream>>>(Wp, pWp, Cn, Cn);
    pack_b_kernel<<<(Cn * FFn + 255) / 256, 256, 0, stream>>>(W1, pW1, Cn, FFn);
    pack_b_kernel<<<(FFn * Cn + 255) / 256, 256, 0, stream>>>(W2, pW2, FFn, Cn);

    // 1) h = LN1(x)
    ln_bf16_kernel<<<M, 128, 0, stream>>>(x, g1, be1, h);
    // 2) qkv
    gemm_mfma<Cn, 1152, 0><<<dim3(18, 256), 256, 0, stream>>>(h, pQKV, nullptr, nullptr, nullptr, big);
    // 3) attention (MFMA flash-style)
    attn_mfma_kernel<<<dim3(4, Bn * Hn), 256, 0, stream>>>(big, big + SECn, big + 2 * SECn, o);
    // 4) x2 = x + o@Wp + bp
    gemm_mfma<Cn, Cn, 1><<<dim3(6, 256), 256, 0, stream>>>(o, pWp, bp, x, x2, nullptr);
    // 5) h2 = LN2(x2)
    ln_bf16_kernel<<<M, 128, 0, stream>>>(x2, g2, be2, h);
    // 6) y1 = relu(h2 @ W1 + b1)
    gemm_mfma<Cn, FFn, 2><<<dim3(24, 256), 256, 0, stream>>>(h, pW1, b1, nullptr, nullptr, big);
    // 7) out = x2 + y1 @ W2 + b2
    gemm_mfma<FFn, Cn, 1><<<dim3(6, 256), 256, 0, stream>>>(big, pW2, b2, x2, x2, nullptr);
}